// Round 6
// baseline (318.343 us; speedup 1.0000x reference)
//
#include <hip/hip_runtime.h>

// OctreeCrossEntropyLoss on gfx950 — ONE fused kernel.
//
// R5 lessons: dur_us contains ~140us of fixed harness cost (512MB ws re-poison
// @78us + ~60us input restore). Our kernels ~78us vs 31us BW floor (192MB).
// This round: single dispatch (last-WG cascade via threadfence+atomic; counter
// uses the documented 0xAA ws poison as its initial value), 2048 WGs x 2
// blocks, launch_bounds(256,3) for 3 WGs/CU residency, all 24 loads in
// flight before the single barrier.

#define W_INSIDE 16.0f

typedef int   vint4   __attribute__((ext_vector_type(4)));
typedef float vfloat4 __attribute__((ext_vector_type(4)));

__global__ __launch_bounds__(256, 3) void main_kernel(
    const int* __restrict__ gt,
    const float* __restrict__ preds,
    const float* __restrict__ ps,              // preds_single (585,3)
    float* __restrict__ loss,                  // ws: 4096 per-block losses
    unsigned char* __restrict__ flags,         // ws: 4096 per-block flags
    unsigned* __restrict__ counter,            // ws: poisoned to 0xAAAAAAAA
    float* __restrict__ out)
{
    const int w = blockIdx.x;                  // 0..2047
    const int t = threadIdx.x;                 // 0..255
    const int bi = w >> 7, bj = (w >> 3) & 15, h = w & 7;
    const int n0 = bi * 256 + bj * 16 + 2 * h; // first of 2 blocks

    // ---- issue preds loads for block 0 (8 x 16B, coalesced) ----
    const vfloat4* __restrict__ pb = reinterpret_cast<const vfloat4*>(preds) + (size_t)n0 * 2048;
    vfloat4 A[8], B[8];
    #pragma unroll
    for (int j = 0; j < 4; ++j) {
        A[j]     = __builtin_nontemporal_load(pb + t + 256 * j);
        A[4 + j] = __builtin_nontemporal_load(pb + 1024 + t + 256 * j);
    }

    // ---- issue 8 coalesced gt int4 loads (32KB slab: 16x,16y,32z) ----
    // int4 idx = x*16384 + y*64 + 8h + Z8; thread t covers Xhi=t>>7, Y=(t>>3)&15, Z8=t&7
    const vint4* __restrict__ gt4 = reinterpret_cast<const vint4*>(gt);
    const int gbase = (16 * bi + (t >> 7)) * 16384 + (16 * bj + ((t >> 3) & 15)) * 64
                    + 8 * h + (t & 7);
    vint4 G[8];
    #pragma unroll
    for (int i = 0; i < 8; ++i)
        G[i] = __builtin_nontemporal_load(gt4 + gbase + (2 * i) * 16384);   // X = 2i + (t>>7)

    // ---- issue preds loads for block 1 (before the barrier: stays in flight) ----
    #pragma unroll
    for (int j = 0; j < 4; ++j) {
        B[j]     = __builtin_nontemporal_load(pb + 2048 + t + 256 * j);
        B[4 + j] = __builtin_nontemporal_load(pb + 3072 + t + 256 * j);
    }
    __builtin_amdgcn_sched_barrier(0);

    // ---- pack gt bits into LDS nibble table: nib[X*128 + Y*8 + Z8] (2KB) ----
    __shared__ unsigned char nib[2048];
    {
        const int nbase = (t >> 7) * 128 + ((t >> 3) & 15) * 8 + (t & 7);
        #pragma unroll
        for (int i = 0; i < 8; ++i) {
            const unsigned m = (G[i].x & 1) | ((G[i].y & 1) << 1)
                             | ((G[i].z & 1) << 2) | ((G[i].w & 1) << 3);
            nib[nbase + 2 * i * 128] = (unsigned char)m;
        }
    }
    __syncthreads();

    // ---- per-block compute ----
    float wnll[2];
    int   c1[2];
    #define COMP(SRC, kk)                                                          \
    {                                                                              \
        float wn = 0.0f; int cc = 0;                                               \
        _Pragma("unroll")                                                          \
        for (int j = 0; j < 4; ++j) {                                              \
            const int g = t + 256 * j;                                             \
            const unsigned bits =                                                  \
                nib[(g >> 6) * 128 + ((g >> 2) & 15) * 8 + (kk) * 4 + (g & 3)];    \
            cc += __builtin_popcount(bits);                                        \
            const float av[4] = {SRC[j].x, SRC[j].y, SRC[j].z, SRC[j].w};          \
            const float bv[4] = {SRC[4+j].x, SRC[4+j].y, SRC[4+j].z, SRC[4+j].w};  \
            _Pragma("unroll")                                                      \
            for (int j2 = 0; j2 < 4; ++j2) {                                       \
                const int tg = (bits >> j2) & 1;                                   \
                const float d   = tg ? (bv[j2] - av[j2]) : (av[j2] - bv[j2]);      \
                const float nll = fmaxf(-d, 0.0f) + __logf(1.0f + __expf(-fabsf(d))); \
                wn += tg ? nll : W_INSIDE * nll;                                   \
            }                                                                      \
        }                                                                          \
        wnll[kk] = wn; c1[kk] = cc;                                                \
    }
    COMP(A, 0)
    COMP(B, 1)
    #undef COMP

    // ---- reductions: 2 quantities x 2 blocks ----
    __shared__ float s_w[2][4];
    __shared__ int   s_c[2][4];
    const int wave = t >> 6;
    #pragma unroll
    for (int k = 0; k < 2; ++k) {
        float wv = wnll[k];
        int   cv = c1[k];
        #pragma unroll
        for (int off = 32; off > 0; off >>= 1) {
            wv += __shfl_down(wv, off, 64);
            cv += __shfl_down(cv, off, 64);
        }
        if ((t & 63) == 0) { s_w[k][wave] = wv; s_c[k][wave] = cv; }
    }
    __syncthreads();
    if (t < 2) {
        const float W = (s_w[t][0] + s_w[t][1]) + (s_w[t][2] + s_w[t][3]);
        const int   C = (s_c[t][0] + s_c[t][1]) + (s_c[t][2] + s_c[t][3]);
        loss[n0 + t]  = W / (65536.0f - 15.0f * (float)C);
        flags[n0 + t] = (unsigned char)((C == 4096 ? 1 : 0) | (C > 0 ? 2 : 0));
        __threadfence();   // release: make loss/flags visible device-wide
    }
    __syncthreads();

    // ---- last-WG cascade (levels 1..4 + final sum) ----
    __shared__ unsigned s_last;
    if (t == 0) {
        const unsigned old = atomicAdd(counter, 1u);
        s_last = (old == 0xAAAAAAAAu + 2047u) ? 1u : 0u;   // ws poison = 0xAA
    }
    __syncthreads();
    if (s_last) {
        __threadfence();   // acquire: invalidate stale caches

        __shared__ unsigned char s1[512];
        __shared__ unsigned char s2[64];
        __shared__ unsigned char s3[8];
        float acc = 0.0f;

        // level-0 loss sum: 16 floats per thread
        #pragma unroll
        for (int j = 0; j < 4; ++j) {
            const vfloat4 l = *(reinterpret_cast<const vfloat4*>(loss) + 4 * t + j);
            acc += (l.x + l.y) + (l.z + l.w);
        }

        // level 1: 512 nodes, 2 per thread
        #pragma unroll
        for (int r = 0; r < 2; ++r) {
            const int u = t + 256 * r;
            const int ci = u >> 6, cj = (u >> 3) & 7, ck = u & 7;
            int mn = 1, mx = 0;
            #pragma unroll
            for (int di = 0; di < 2; ++di)
            #pragma unroll
            for (int dj = 0; dj < 2; ++dj)
            #pragma unroll
            for (int dk = 0; dk < 2; ++dk) {
                const unsigned char c = flags[(2*ci+di)*256 + (2*cj+dj)*16 + (2*ck+dk)];
                mn &= (c & 1);
                mx |= ((c >> 1) & 1);
            }
            const int g = (mn == mx) ? mx : 2;
            acc += __logf(ps[u * 3 + g]);
            s1[u] = (unsigned char)(mn | (mx << 1));
        }
        __syncthreads();

        // level 2: 64 nodes
        if (t < 64) {
            const int ci = t >> 4, cj = (t >> 2) & 3, ck = t & 3;
            int mn = 1, mx = 0;
            #pragma unroll
            for (int di = 0; di < 2; ++di)
            #pragma unroll
            for (int dj = 0; dj < 2; ++dj)
            #pragma unroll
            for (int dk = 0; dk < 2; ++dk) {
                const unsigned char c = s1[(2*ci+di)*64 + (2*cj+dj)*8 + (2*ck+dk)];
                mn &= (c & 1);
                mx |= ((c >> 1) & 1);
            }
            const int g = (mn == mx) ? mx : 2;
            acc += __logf(ps[(512 + t) * 3 + g]);
            s2[t] = (unsigned char)(mn | (mx << 1));
        }
        __syncthreads();

        // level 3: 8 nodes
        if (t < 8) {
            const int ci = t >> 2, cj = (t >> 1) & 1, ck = t & 1;
            int mn = 1, mx = 0;
            #pragma unroll
            for (int di = 0; di < 2; ++di)
            #pragma unroll
            for (int dj = 0; dj < 2; ++dj)
            #pragma unroll
            for (int dk = 0; dk < 2; ++dk) {
                const unsigned char c = s2[(2*ci+di)*16 + (2*cj+dj)*4 + (2*ck+dk)];
                mn &= (c & 1);
                mx |= ((c >> 1) & 1);
            }
            const int g = (mn == mx) ? mx : 2;
            acc += __logf(ps[(576 + t) * 3 + g]);
            s3[t] = (unsigned char)(mn | (mx << 1));
        }
        __syncthreads();

        // level 4: root
        if (t == 0) {
            int mn = 1, mx = 0;
            #pragma unroll
            for (int c8 = 0; c8 < 8; ++c8) {
                mn &= (s3[c8] & 1);
                mx |= ((s3[c8] >> 1) & 1);
            }
            const int g = (mn == mx) ? mx : 2;
            acc += __logf(ps[584 * 3 + g]);
        }

        // reduce over 4 waves, single store
        #pragma unroll
        for (int off = 32; off > 0; off >>= 1)
            acc += __shfl_down(acc, off, 64);
        __shared__ float s_acc[4];
        if ((t & 63) == 0) s_acc[wave] = acc;
        __syncthreads();
        if (t == 0)
            out[0] = (s_acc[0] + s_acc[1]) + (s_acc[2] + s_acc[3]);
    }
}

extern "C" void kernel_launch(void* const* d_in, const int* in_sizes, int n_in,
                              void* d_out, int out_size, void* d_ws, size_t ws_size,
                              hipStream_t stream) {
    const int*   gt    = (const int*)d_in[0];      // (1,256,256,256) int32
    const float* preds = (const float*)d_in[1];    // (4096,2,16,16,16) f32
    const float* ps    = (const float*)d_in[2];    // (585,3) f32
    float* out = (float*)d_out;

    float*         loss    = (float*)d_ws;                         // 16 KB
    unsigned char* flagbuf = (unsigned char*)d_ws + 16384;         // 4 KB
    unsigned*      counter = (unsigned*)((char*)d_ws + 20480);     // 4 B (poisoned 0xAA)

    main_kernel<<<2048, 256, 0, stream>>>(gt, preds, ps, loss, flagbuf, counter, out);
}

// Round 7
// 217.689 us; speedup vs baseline: 1.4624x; 1.4624x over previous
//
#include <hip/hip_runtime.h>

// OctreeCrossEntropyLoss on gfx950 — fused main kernel + tiny levels kernel.
//
// R6 lessons: (a) launch_bounds(256,3) capped VGPR at 52 -> compiler sank
// loads past sched_barrier (IR-level sinking ignores it) and re-serialized;
// (b) __threadfence on multi-XCD gfx950 emits per-WG L2 writebacks -> 2048
// L2 flushes; (c) WRITE_SIZE=189MB shows the harness input-restore's dirty
// L2 lines drain to HBM during our window -> practical floor is
// ~382MB / 6.3TB/s ~= 61us for the main kernel, not 31us.
//
// This round: R5 structure (1024 WGs x 4 blocks, (256,2), separate levels
// kernel, no fences/atomics) + asm volatile memory barriers, which IR
// passes cannot move loads across, pinning all loads in flight before
// any consumer.

#define W_INSIDE 16.0f

typedef int   vint4   __attribute__((ext_vector_type(4)));
typedef float vfloat4 __attribute__((ext_vector_type(4)));

#define LOAD_FENCE() asm volatile("" ::: "memory")

__global__ __launch_bounds__(256, 2) void main_kernel(
    const int* __restrict__ gt,
    const float* __restrict__ preds,
    float* __restrict__ loss,                  // 4096 per-block losses
    unsigned char* __restrict__ flags)         // 4096 per-block min/max flags
{
    const int w = blockIdx.x;                  // 0..1023
    const int t = threadIdx.x;                 // 0..255
    const int bi = w >> 6, bj = (w >> 2) & 15, q = w & 3;
    const int n0 = bi * 256 + bj * 16 + 4 * q; // first of 4 blocks

    // ---- issue 16 coalesced gt int4 loads (whole 64KB slab) ----
    // slab voxel (X,Y,zl): x=16bi+X, y=16bj+Y, z=64q+zl. int4 idx =
    // x*16384 + y*64 + 16q + Z4, thread t covers Y=t>>4, Z4=t&15, X=i.
    const vint4* __restrict__ gt4 = reinterpret_cast<const vint4*>(gt);
    const int gbase = bi * 262144 + bj * 1024 + (t >> 4) * 64 + 16 * q + (t & 15);
    vint4 G[16];
    #pragma unroll
    for (int i = 0; i < 16; ++i)
        G[i] = __builtin_nontemporal_load(gt4 + gbase + i * 16384);

    // ---- issue preds loads for block k=0 (8 x 16B, coalesced) ----
    const vfloat4* __restrict__ pb = reinterpret_cast<const vfloat4*>(preds) + (size_t)n0 * 2048;
    vfloat4 A[8], B[8];
    #define LOAD8(DST, kk)                                                         \
    {                                                                              \
        _Pragma("unroll")                                                          \
        for (int j = 0; j < 4; ++j) {                                              \
            DST[j]     = __builtin_nontemporal_load(pb + (kk) * 2048 + t + 256 * j);          \
            DST[4 + j] = __builtin_nontemporal_load(pb + (kk) * 2048 + 1024 + t + 256 * j);   \
        }                                                                          \
    }
    LOAD8(A, 0)
    LOAD_FENCE();   // loads above cannot sink below; LDS writes below cannot hoist above

    // ---- pack gt bits into LDS nibble table: nib[X*256 + Y*16 + Z4] ----
    __shared__ unsigned char nib[4096];
    #pragma unroll
    for (int i = 0; i < 16; ++i) {
        const unsigned m = (G[i].x & 1) | ((G[i].y & 1) << 1)
                         | ((G[i].z & 1) << 2) | ((G[i].w & 1) << 3);
        nib[i * 256 + t] = (unsigned char)m;
    }
    __syncthreads();

    float wnll[4];
    int   c1[4];

    // per-block compute: voxel group g = t+256j covers x=g>>6, y=(g>>2)&15,
    // z = (g&3)*4 + j2 within block k; nibble = nib[(g>>6)*256 +
    // ((g>>2)&15)*16 + k*4 + (g&3)].
    #define COMP(SRC, kk)                                                          \
    {                                                                              \
        float wn = 0.0f; int cc = 0;                                               \
        _Pragma("unroll")                                                          \
        for (int j = 0; j < 4; ++j) {                                              \
            const int g = t + 256 * j;                                             \
            const unsigned bits =                                                  \
                nib[(g >> 6) * 256 + ((g >> 2) & 15) * 16 + (kk) * 4 + (g & 3)];   \
            cc += __builtin_popcount(bits);                                        \
            const float av[4] = {SRC[j].x, SRC[j].y, SRC[j].z, SRC[j].w};          \
            const float bv[4] = {SRC[4+j].x, SRC[4+j].y, SRC[4+j].z, SRC[4+j].w};  \
            _Pragma("unroll")                                                      \
            for (int j2 = 0; j2 < 4; ++j2) {                                       \
                const int tg = (bits >> j2) & 1;                                   \
                const float d   = tg ? (bv[j2] - av[j2]) : (av[j2] - bv[j2]);      \
                const float nll = fmaxf(-d, 0.0f) + __logf(1.0f + __expf(-fabsf(d))); \
                wn += tg ? nll : W_INSIDE * nll;                                   \
            }                                                                      \
        }                                                                          \
        wnll[kk] = wn; c1[kk] = cc;                                                \
    }

    LOAD8(B, 1) LOAD_FENCE(); COMP(A, 0)
    LOAD8(A, 2) LOAD_FENCE(); COMP(B, 1)
    LOAD8(B, 3) LOAD_FENCE(); COMP(A, 2)
    COMP(B, 3)
    #undef LOAD8
    #undef COMP

    // ---- reductions: 2 quantities x 4 blocks ----
    __shared__ float s_w[4][4];
    __shared__ int   s_c[4][4];
    const int wave = t >> 6;
    #pragma unroll
    for (int k = 0; k < 4; ++k) {
        float wv = wnll[k];
        int   cv = c1[k];
        #pragma unroll
        for (int off = 32; off > 0; off >>= 1) {
            wv += __shfl_down(wv, off, 64);
            cv += __shfl_down(cv, off, 64);
        }
        if ((t & 63) == 0) { s_w[k][wave] = wv; s_c[k][wave] = cv; }
    }
    __syncthreads();
    if (t < 4) {
        const float W = (s_w[t][0] + s_w[t][1]) + (s_w[t][2] + s_w[t][3]);
        const int   C = (s_c[t][0] + s_c[t][1]) + (s_c[t][2] + s_c[t][3]);
        loss[n0 + t]  = W / (65536.0f - 15.0f * (float)C);
        flags[n0 + t] = (unsigned char)((C == 4096 ? 1 : 0) | (C > 0 ? 2 : 0));
    }
}

// ---------- levels 1..4 + final reduction ----------
__global__ __launch_bounds__(512) void levels_kernel(
    const float* __restrict__ loss,
    const unsigned char* __restrict__ flags,
    const float* __restrict__ ps,              // preds_single (585,3)
    float* __restrict__ out)
{
    __shared__ unsigned char s1[512];
    __shared__ unsigned char s2[64];
    __shared__ unsigned char s3[8];
    const int t = threadIdx.x;
    float acc = 0.0f;

    // level-0 loss reduction: 8 floats per thread
    {
        const vfloat4 l0 = *(reinterpret_cast<const vfloat4*>(loss) + 2 * t);
        const vfloat4 l1 = *(reinterpret_cast<const vfloat4*>(loss) + 2 * t + 1);
        acc += (l0.x + l0.y) + (l0.z + l0.w) + (l1.x + l1.y) + (l1.z + l1.w);
    }

    // level 1: nb=8 (512 blocks), children on 16^3 grid
    {
        const int bi = t >> 6, bj = (t >> 3) & 7, bk = t & 7;
        int mn = 1, mx = 0;
        #pragma unroll
        for (int di = 0; di < 2; ++di)
        #pragma unroll
        for (int dj = 0; dj < 2; ++dj)
        #pragma unroll
        for (int dk = 0; dk < 2; ++dk) {
            const unsigned char c = flags[(2*bi+di)*256 + (2*bj+dj)*16 + (2*bk+dk)];
            mn &= (c & 1);
            mx |= ((c >> 1) & 1);
        }
        const int g = (mn == mx) ? mx : 2;
        acc += __logf(ps[(0 + t) * 3 + g]);
        s1[t] = (unsigned char)(mn | (mx << 1));
    }
    __syncthreads();

    // level 2: nb=4 (64 blocks)
    if (t < 64) {
        const int bi = t >> 4, bj = (t >> 2) & 3, bk = t & 3;
        int mn = 1, mx = 0;
        #pragma unroll
        for (int di = 0; di < 2; ++di)
        #pragma unroll
        for (int dj = 0; dj < 2; ++dj)
        #pragma unroll
        for (int dk = 0; dk < 2; ++dk) {
            const unsigned char c = s1[(2*bi+di)*64 + (2*bj+dj)*8 + (2*bk+dk)];
            mn &= (c & 1);
            mx |= ((c >> 1) & 1);
        }
        const int g = (mn == mx) ? mx : 2;
        acc += __logf(ps[(512 + t) * 3 + g]);
        s2[t] = (unsigned char)(mn | (mx << 1));
    }
    __syncthreads();

    // level 3: nb=2 (8 blocks)
    if (t < 8) {
        const int bi = t >> 2, bj = (t >> 1) & 1, bk = t & 1;
        int mn = 1, mx = 0;
        #pragma unroll
        for (int di = 0; di < 2; ++di)
        #pragma unroll
        for (int dj = 0; dj < 2; ++dj)
        #pragma unroll
        for (int dk = 0; dk < 2; ++dk) {
            const unsigned char c = s2[(2*bi+di)*16 + (2*bj+dj)*4 + (2*bk+dk)];
            mn &= (c & 1);
            mx |= ((c >> 1) & 1);
        }
        const int g = (mn == mx) ? mx : 2;
        acc += __logf(ps[(576 + t) * 3 + g]);
        s3[t] = (unsigned char)(mn | (mx << 1));
    }
    __syncthreads();

    // level 4
    if (t == 0) {
        int mn = 1, mx = 0;
        #pragma unroll
        for (int c8 = 0; c8 < 8; ++c8) {
            mn &= (s3[c8] & 1);
            mx |= ((s3[c8] >> 1) & 1);
        }
        const int g = (mn == mx) ? mx : 2;
        acc += __logf(ps[584 * 3 + g]);
    }

    // reduce over 512 threads, single plain store
    #pragma unroll
    for (int off = 32; off > 0; off >>= 1)
        acc += __shfl_down(acc, off, 64);
    __shared__ float s_acc[8];
    const int wave = t >> 6;
    if ((t & 63) == 0) s_acc[wave] = acc;
    __syncthreads();
    if (t == 0) {
        float S = 0.0f;
        #pragma unroll
        for (int w8 = 0; w8 < 8; ++w8) S += s_acc[w8];
        out[0] = S;
    }
}

extern "C" void kernel_launch(void* const* d_in, const int* in_sizes, int n_in,
                              void* d_out, int out_size, void* d_ws, size_t ws_size,
                              hipStream_t stream) {
    const int*   gt    = (const int*)d_in[0];      // (1,256,256,256) int32
    const float* preds = (const float*)d_in[1];    // (4096,2,16,16,16) f32
    const float* ps    = (const float*)d_in[2];    // (585,3) f32
    float* out = (float*)d_out;

    float*         loss    = (float*)d_ws;                  // 16 KB
    unsigned char* flagbuf = (unsigned char*)d_ws + 16384;  // 4 KB

    main_kernel<<<1024, 256, 0, stream>>>(gt, preds, loss, flagbuf);
    levels_kernel<<<1, 512, 0, stream>>>(loss, flagbuf, ps, out);
}